// Round 3
// baseline (1546.368 us; speedup 1.0000x reference)
//
#include <hip/hip_runtime.h>
#include <math.h>

// ---------------------------------------------------------------------------
// RLIPv2 BiMultiHeadAttention. Round 3: dtype-adaptive correctness build.
//  - Device-side dtype sniffer: attention_mask_v == 1.0s; first u32 is
//    0x3F800000 iff inputs are fp32, 0x3F803F80 iff bf16. All kernels that
//    touch d_in/d_out branch (wave-uniformly) on the flag.
//  - Intermediates (q, val_v, k, val_l, attn_v, attn_l) always bf16 in ws.
//  - ws-adaptive: nchunk for dir-l flash shrinks to fit ws_size; q spills to
//    the d_out region (dead before out-projections) if ws is tight.
//  - dir-l partial records: 32 bf16 accs + fp32 m,l = 72 B.
// ---------------------------------------------------------------------------

typedef unsigned short u16;
typedef unsigned int   u32;
typedef __attribute__((ext_vector_type(4))) u16 us4;
typedef __attribute__((ext_vector_type(8))) u16 us8;

#define B_   4
#define TV_  13600
#define TL_  256
#define VD_  256
#define LD_  768
#define E_   256
#define H_   8
#define HD_  32
#define PREC 36          // partial record u16 stride (72 B)

static constexpr float SCALE_  = 0.17677669529663687f;  // 32^-0.5
static constexpr float CLAMP_  = 50000.0f;
static constexpr float NEG_    = -9e15f;
static constexpr float LOG2E_  = 1.4426950408889634f;

__device__ __forceinline__ float bf2f(u16 x) {
    return __uint_as_float(((u32)x) << 16);
}
__device__ __forceinline__ u16 f2bf(float f) {           // RNE
    u32 u = __float_as_uint(f);
    u += 0x7fffu + ((u >> 16) & 1u);
    return (u16)(u >> 16);
}

// dtype-flexible element access -----------------------------------------------
template<bool F32> __device__ __forceinline__ float ld1(const void* p, size_t i) {
    if constexpr (F32) return ((const float*)p)[i];
    else               return bf2f(((const u16*)p)[i]);
}
template<bool F32> __device__ __forceinline__ void ld4(const void* p, size_t i, float o[4]) {
    if constexpr (F32) {
        float4 v = *(const float4*)((const float*)p + i);
        o[0]=v.x; o[1]=v.y; o[2]=v.z; o[3]=v.w;
    } else {
        us4 v = *(const us4*)((const u16*)p + i);
        o[0]=bf2f(v[0]); o[1]=bf2f(v[1]); o[2]=bf2f(v[2]); o[3]=bf2f(v[3]);
    }
}
template<bool F32> __device__ __forceinline__ void st4(void* p, size_t i, const float v[4]) {
    if constexpr (F32) {
        float4 t; t.x=v[0]; t.y=v[1]; t.z=v[2]; t.w=v[3];
        *(float4*)((float*)p + i) = t;
    } else {
        us4 t; t[0]=f2bf(v[0]); t[1]=f2bf(v[1]); t[2]=f2bf(v[2]); t[3]=f2bf(v[3]);
        *(us4*)((u16*)p + i) = t;
    }
}

// ---------------------------------------------------------------------------
__global__ void sniff_kernel(const void* __restrict__ mask, int* __restrict__ flag) {
    if (threadIdx.x == 0 && blockIdx.x == 0) {
        u32 w = *(const u32*)mask;          // mask values are exactly 1.0f
        *flag = (w == 0x3F800000u) ? 1 : 0; // fp32 1.0 vs packed bf16 (1.0,1.0)
    }
}

// ---------------------------------------------------------------------------
// NT GEMM: C[m,n] = (sum_k (A[m,k](+A2)) * W[n,k] + bias[n]) * scale
// 64x64 tile, BK=16, 4x4 micro. M%64==0, N%64==0, K%16==0.
// ---------------------------------------------------------------------------
template<bool AF32, bool WF32, bool CF32, bool HAS_A2>
__device__ __forceinline__ void gemm_body(
    const void* A, const void* A2, const void* W, const void* Wb,
    void* C, size_t c_off, int M, int N, int K, float scale,
    float (*As)[17], float (*Ws)[17])
{
    const int tid  = threadIdx.x;
    const size_t row0 = (size_t)blockIdx.x * 64;
    const int col0 = blockIdx.y * 64;
    const int tm = tid >> 4, tn = tid & 15;
    const int lr = tid >> 2;
    const int lk = (tid & 3) << 2;

    float acc[4][4] = {};

    for (int k0 = 0; k0 < K; k0 += 16) {
        float a4[4];
        ld4<AF32>(A, (row0 + lr) * (size_t)K + k0 + lk, a4);
        if constexpr (HAS_A2) {
            float b4[4];
            ld4<AF32>(A2, (row0 + lr) * (size_t)K + k0 + lk, b4);
            #pragma unroll
            for (int j = 0; j < 4; ++j) a4[j] += b4[j];
        }
        #pragma unroll
        for (int j = 0; j < 4; ++j) As[lr][lk + j] = a4[j];

        float w4[4];
        ld4<WF32>(W, ((size_t)col0 + lr) * (size_t)K + k0 + lk, w4);
        #pragma unroll
        for (int j = 0; j < 4; ++j) Ws[lr][lk + j] = w4[j];

        __syncthreads();
        #pragma unroll
        for (int kk = 0; kk < 16; ++kk) {
            float a0 = As[tm*4+0][kk], a1 = As[tm*4+1][kk];
            float a2 = As[tm*4+2][kk], a3 = As[tm*4+3][kk];
            float w0 = Ws[tn*4+0][kk], w1 = Ws[tn*4+1][kk];
            float w2 = Ws[tn*4+2][kk], w3 = Ws[tn*4+3][kk];
            acc[0][0] += a0*w0; acc[0][1] += a0*w1; acc[0][2] += a0*w2; acc[0][3] += a0*w3;
            acc[1][0] += a1*w0; acc[1][1] += a1*w1; acc[1][2] += a1*w2; acc[1][3] += a1*w3;
            acc[2][0] += a2*w0; acc[2][1] += a2*w1; acc[2][2] += a2*w2; acc[2][3] += a2*w3;
            acc[3][0] += a3*w0; acc[3][1] += a3*w1; acc[3][2] += a3*w2; acc[3][3] += a3*w3;
        }
        __syncthreads();
    }
    float bw[4];
    #pragma unroll
    for (int j = 0; j < 4; ++j) bw[j] = ld1<WF32>(Wb, col0 + tn*4 + j);
    #pragma unroll
    for (int i = 0; i < 4; ++i) {
        float o4[4];
        #pragma unroll
        for (int j = 0; j < 4; ++j) o4[j] = (acc[i][j] + bw[j]) * scale;
        st4<CF32>(C, c_off + (row0 + tm*4 + i) * (size_t)N + col0 + tn*4, o4);
    }
}

template<bool A_EXT, bool C_EXT, bool HAS_A2>
__global__ __launch_bounds__(256) void gemm_nt(
    const int* __restrict__ flag,
    const void* __restrict__ A, const void* __restrict__ A2,
    const void* __restrict__ W, const void* __restrict__ Wb,
    void* __restrict__ C, size_t c_off, int M, int N, int K, float scale)
{
    __shared__ float As[64][17];
    __shared__ float Ws[64][17];
    if (*flag) gemm_body<A_EXT, true,  C_EXT, HAS_A2>(A, A2, W, Wb, C, c_off, M, N, K, scale, As, Ws);
    else       gemm_body<false, false, false, HAS_A2>(A, A2, W, Wb, C, c_off, M, N, K, scale, As, Ws);
}

// ---------------------------------------------------------------------------
// Dir-v fused attention: grid (425, H, B), 256 threads; 32 t-rows x 256 s.
// ---------------------------------------------------------------------------
template<bool MF32>
__device__ __forceinline__ void attn_v_body(
    const u16* qm, const u16* km, const u16* vm, const void* maskl,
    u16* outm, u16* smem, float (*S)[257], float* mls, float* rowsum)
{
    u16 (*QsT)[36]  = (u16(*)[36])smem;            // [kk][t]
    u16 (*KsT)[256] = (u16(*)[256])(smem + 1152);  // [kk][s]
    u16 (*Vs)[40]   = (u16(*)[40])smem;            // [s][d] (phase B overlay)

    const int bb = blockIdx.z, hh = blockIdx.y;
    const int t0 = blockIdx.x * 32;
    const int tid = threadIdx.x;

    {   // stage Q^T
        int row = tid >> 3;
        int d0  = (tid & 7) * 4;
        us4 qv = *(const us4*)(qm + ((size_t)(bb*TV_ + t0 + row) * E_ + hh*HD_ + d0));
        QsT[d0+0][row] = qv[0]; QsT[d0+1][row] = qv[1];
        QsT[d0+2][row] = qv[2]; QsT[d0+3][row] = qv[3];
    }
    {   // stage K^T + mask
        int s = tid;
        const u16* p = km + ((size_t)(bb*TL_ + s) * E_ + hh*HD_);
        #pragma unroll
        for (int d0 = 0; d0 < 32; d0 += 8) {
            us8 kv = *(const us8*)(p + d0);
            #pragma unroll
            for (int j = 0; j < 8; ++j) KsT[d0+j][s] = kv[j];
        }
        float mlv = ld1<MF32>(maskl, (size_t)bb*TL_ + s);
        mls[s] = (mlv == 0.0f) ? NEG_ : mlv;
    }
    __syncthreads();

    {   // S = q.k^T, clamp
        const int tm = tid >> 5;
        const int tn = tid & 31;
        float sacc[4][8] = {};
        #pragma unroll
        for (int kk = 0; kk < 32; ++kk) {
            us4 qa = *(const us4*)&QsT[kk][tm*4];
            float a0 = bf2f(qa[0]), a1 = bf2f(qa[1]), a2 = bf2f(qa[2]), a3 = bf2f(qa[3]);
            us8 kb = *(const us8*)&KsT[kk][tn*8];
            float w[8];
            #pragma unroll
            for (int j = 0; j < 8; ++j) w[j] = bf2f(kb[j]);
            #pragma unroll
            for (int j = 0; j < 8; ++j) {
                sacc[0][j] += a0*w[j]; sacc[1][j] += a1*w[j];
                sacc[2][j] += a2*w[j]; sacc[3][j] += a3*w[j];
            }
        }
        #pragma unroll
        for (int i = 0; i < 4; ++i)
            #pragma unroll
            for (int j = 0; j < 8; ++j)
                S[tm*4+i][tn*8+j] = fminf(fmaxf(sacc[i][j], -CLAMP_), CLAMP_);
    }
    __syncthreads();

    {   // stage V (overlay)
        int s = tid;
        const u16* p = vm + ((size_t)(bb*TL_ + s) * E_ + hh*HD_);
        #pragma unroll
        for (int d0 = 0; d0 < 32; d0 += 8)
            *(us8*)&Vs[s][d0] = *(const us8*)(p + d0);
    }
    {   // softmax over s (8 lanes per row)
        int row = tid >> 3;
        int l8  = tid & 7;
        float mx = -1e30f;
        #pragma unroll
        for (int j = 0; j < 32; ++j) {
            int s = j*8 + l8;
            mx = fmaxf(mx, S[row][s] + mls[s]);
        }
        mx = fmaxf(mx, __shfl_xor(mx, 1));
        mx = fmaxf(mx, __shfl_xor(mx, 2));
        mx = fmaxf(mx, __shfl_xor(mx, 4));
        float sum = 0.f;
        #pragma unroll
        for (int j = 0; j < 32; ++j) {
            int s = j*8 + l8;
            float p = exp2f((S[row][s] + mls[s] - mx) * LOG2E_);
            S[row][s] = p;
            sum += p;
        }
        sum += __shfl_xor(sum, 1);
        sum += __shfl_xor(sum, 2);
        sum += __shfl_xor(sum, 4);
        if (l8 == 0) rowsum[row] = sum;
    }
    __syncthreads();

    {   // out = P @ V
        int tr = tid >> 3;
        int dg = tid & 7;
        float a0 = 0.f, a1 = 0.f, a2 = 0.f, a3 = 0.f;
        #pragma unroll 8
        for (int s = 0; s < 256; ++s) {
            float p = S[tr][s];
            us4 vv = *(const us4*)&Vs[s][dg*4];
            a0 += p * bf2f(vv[0]); a1 += p * bf2f(vv[1]);
            a2 += p * bf2f(vv[2]); a3 += p * bf2f(vv[3]);
        }
        float inv = 1.0f / rowsum[tr];
        us4 o;
        o[0] = f2bf(a0*inv); o[1] = f2bf(a1*inv);
        o[2] = f2bf(a2*inv); o[3] = f2bf(a3*inv);
        *(us4*)(outm + ((size_t)(bb*TV_ + t0 + tr) * E_ + hh*HD_ + dg*4)) = o;
    }
}

__global__ __launch_bounds__(256) void attn_v_kernel(
    const int* __restrict__ flag,
    const u16* __restrict__ qm, const u16* __restrict__ km,
    const u16* __restrict__ vm, const void* __restrict__ maskl,
    u16* __restrict__ outm)
{
    __shared__ __align__(16) u16 smem[10240];
    __shared__ float S[32][257];
    __shared__ float mls[256];
    __shared__ float rowsum[32];
    if (*flag) attn_v_body<true >(qm, km, vm, maskl, outm, smem, S, mls, rowsum);
    else       attn_v_body<false>(qm, km, vm, maskl, outm, smem, S, mls, rowsum);
}

// ---------------------------------------------------------------------------
// Dir-l flash partials: grid (nchunk, H, B), 256 threads, thread = s row.
// Record: 32 bf16 accs + fp32 m + fp32 l (72 B).
// ---------------------------------------------------------------------------
template<bool MF32>
__device__ __forceinline__ void attn_l_body(
    const u16* qm, const u16* km, const u16* vm, const void* maskv,
    u16* part, int nchunk, int chunk,
    float (*Qc)[36], float (*Vc)[36], float* mvc)
{
    const int bb = blockIdx.z, hh = blockIdx.y, tc = blockIdx.x;
    const int tid = threadIdx.x;
    const int s = tid;

    float kr[32];
    {
        const u16* p = km + ((size_t)(bb*TL_ + s) * E_ + hh*HD_);
        #pragma unroll
        for (int d0 = 0; d0 < 32; d0 += 8) {
            us8 kv = *(const us8*)(p + d0);
            #pragma unroll
            for (int j = 0; j < 8; ++j) kr[d0+j] = bf2f(kv[j]);
        }
    }
    float m = -1e30f, lsum = 0.f;
    float acc[32];
    #pragma unroll
    for (int d = 0; d < 32; ++d) acc[d] = 0.f;

    const int c0 = tc * chunk, c1 = c0 + chunk;
    for (int t0 = c0; t0 < c1; t0 += 64) {
        const int cnt = min(64, c1 - t0);
        {
            int row = tid >> 2;
            int d0  = (tid & 3) * 8;
            if (row < cnt) {
                size_t base = (size_t)(bb*TV_ + t0 + row) * E_ + hh*HD_ + d0;
                us8 qv = *(const us8*)(qm + base);
                us8 vv = *(const us8*)(vm + base);
                #pragma unroll
                for (int j = 0; j < 8; ++j) Qc[row][d0+j] = bf2f(qv[j]);
                #pragma unroll
                for (int j = 0; j < 8; ++j) Vc[row][d0+j] = bf2f(vv[j]);
            }
            if (tid < cnt) {
                float mv = ld1<MF32>(maskv, (size_t)bb*TV_ + t0 + tid);
                mvc[tid] = (mv == 0.0f) ? NEG_ : mv;
            }
        }
        __syncthreads();
        for (int tt = 0; tt < cnt; ++tt) {
            const float4* qr = (const float4*)&Qc[tt][0];
            float sc = 0.f;
            #pragma unroll
            for (int j4 = 0; j4 < 8; ++j4) {
                float4 qv = qr[j4];
                sc += kr[j4*4+0]*qv.x + kr[j4*4+1]*qv.y
                    + kr[j4*4+2]*qv.z + kr[j4*4+3]*qv.w;
            }
            sc = fminf(fmaxf(sc, -CLAMP_), CLAMP_) + mvc[tt];
            if (sc > m) {
                float al = exp2f((m - sc) * LOG2E_);
                lsum *= al;
                #pragma unroll
                for (int d = 0; d < 32; ++d) acc[d] *= al;
                m = sc;
            }
            float p = exp2f((sc - m) * LOG2E_);
            lsum += p;
            const float4* vr = (const float4*)&Vc[tt][0];
            #pragma unroll
            for (int j4 = 0; j4 < 8; ++j4) {
                float4 vv = vr[j4];
                acc[j4*4+0] += p*vv.x; acc[j4*4+1] += p*vv.y;
                acc[j4*4+2] += p*vv.z; acc[j4*4+3] += p*vv.w;
            }
        }
        __syncthreads();
    }
    u16* rec = part + ((size_t)((bb*H_ + hh)*TL_ + s) * nchunk + tc) * PREC;
    #pragma unroll
    for (int d = 0; d < 32; ++d) rec[d] = f2bf(acc[d]);
    *(float*)(rec + 32) = m;
    *(float*)(rec + 34) = lsum;
}

__global__ __launch_bounds__(256) void attn_l_partial(
    const int* __restrict__ flag,
    const u16* __restrict__ qm, const u16* __restrict__ km,
    const u16* __restrict__ vm, const void* __restrict__ maskv,
    u16* __restrict__ part, int nchunk, int chunk)
{
    __shared__ float Qc[64][36];
    __shared__ float Vc[64][36];
    __shared__ float mvc[64];
    if (*flag) attn_l_body<true >(qm, km, vm, maskv, part, nchunk, chunk, Qc, Vc, mvc);
    else       attn_l_body<false>(qm, km, vm, maskv, part, nchunk, chunk, Qc, Vc, mvc);
}

// Merge partials per (b,h,s) row. grid 1024 x 256 (8 rows/block, 32 lanes/row).
__global__ __launch_bounds__(256) void attn_l_merge(
    const u16* __restrict__ part, u16* __restrict__ outm, int nchunk)
{
    const int R = blockIdx.x * 8 + (threadIdx.x >> 5);
    const int d = threadIdx.x & 31;
    const u16* rec0 = part + (size_t)R * nchunk * PREC;
    float m = -1e30f;
    for (int c = 0; c < nchunk; ++c)
        m = fmaxf(m, *(const float*)(rec0 + c*PREC + 32));
    float L = 0.f, o = 0.f;
    for (int c = 0; c < nchunk; ++c) {
        float mc = *(const float*)(rec0 + c*PREC + 32);
        float lc = *(const float*)(rec0 + c*PREC + 34);
        float w  = exp2f((mc - m) * LOG2E_);
        L += lc * w;
        o += bf2f(rec0[c*PREC + d]) * w;
    }
    o /= L;
    const int bb = R >> 11, hh = (R >> 8) & 7, ss = R & 255;
    outm[(size_t)(bb*TL_ + ss) * E_ + hh*HD_ + d] = f2bf(o);
}

// ---------------------------------------------------------------------------
extern "C" void kernel_launch(void* const* d_in, const int* in_sizes, int n_in,
                              void* d_out, int out_size, void* d_ws, size_t ws_size,
                              hipStream_t stream)
{
    const void* v     = d_in[0];
    const void* l     = d_in[1];
    const void* vpos  = d_in[2];
    const void* maskv = d_in[3];
    const void* maskl = d_in[4];
    const void* Wq  = d_in[5];   const void* bq  = d_in[6];
    const void* Wk  = d_in[7];   const void* bk  = d_in[8];
    const void* Wvv = d_in[9];   const void* bvv = d_in[10];
    const void* Wvl = d_in[11];  const void* bvl = d_in[12];
    const void* Wov = d_in[13];  const void* bov = d_in[14];
    const void* Wol = d_in[15];  const void* bol = d_in[16];

    const size_t TLBUF = (size_t)B_*TL_*E_*2;     // 524,288 B
    const size_t BIG   = (size_t)B_*TV_*E_*2;     // 27,852,800 B
    auto part_bytes = [](int nc) { return (size_t)B_*H_*TL_ * (size_t)nc * (PREC*2); };

    // pick nchunk (and q placement) to fit ws_size
    int nchunk = 16;
    bool q_in_out = false;
    for (;;) {
        size_t need = 512 + (BIG + 256) + 3*(TLBUF + 256) + (part_bytes(nchunk) + 256)
                    + (q_in_out ? 0 : (BIG + 256));
        if (need <= ws_size) break;
        if (nchunk > 1)        nchunk >>= 1;
        else if (!q_in_out)  { q_in_out = true; nchunk = 16; }
        else break;   // hopeless; proceed (will overflow, but nothing else to do)
    }
    const int chunk = TV_ / nchunk;   // 16->850, 8->1700, 4->3400, 2->6800, 1->13600

    char* ws = (char*)d_ws;
    size_t off = 0;
    auto carve = [&](size_t bytes) -> char* {
        char* p = ws + off;
        off += (bytes + 255) & ~(size_t)255;
        return p;
    };
    int*  flag    = (int*)carve(512);
    u16*  valv_ws = (u16*)carve(BIG);
    u16*  k_ws    = (u16*)carve(TLBUF);
    u16*  vall_ws = (u16*)carve(TLBUF);
    u16*  attnl_ws= (u16*)carve(TLBUF);
    u16*  part_ws = (u16*)carve(part_bytes(nchunk));
    u16*  q_ws    = q_in_out ? (u16*)d_out : (u16*)carve(BIG);
    u16*  attnv_ws= valv_ws;   // valv dead after attn_l_partial

    const dim3 blk(256);
    const size_t outl_off = (size_t)B_*TV_*VD_;   // element offset of out_l

    sniff_kernel<<<1, 64, 0, stream>>>(maskv, flag);

    // projections (A external, C internal bf16)
    gemm_nt<true, false, true ><<<dim3(850, 4), blk, 0, stream>>>(flag, v, vpos,    Wq,  bq,  q_ws,    0, B_*TV_, E_, VD_, SCALE_);
    gemm_nt<true, false, false><<<dim3(850, 4), blk, 0, stream>>>(flag, v, nullptr, Wvv, bvv, valv_ws, 0, B_*TV_, E_, VD_, 1.0f);
    gemm_nt<true, false, false><<<dim3(16,  4), blk, 0, stream>>>(flag, l, nullptr, Wk,  bk,  k_ws,    0, B_*TL_, E_, LD_, 1.0f);
    gemm_nt<true, false, false><<<dim3(16,  4), blk, 0, stream>>>(flag, l, nullptr, Wvl, bvl, vall_ws, 0, B_*TL_, E_, LD_, 1.0f);

    // dir-l first (consumes valv), then dir-v (attnv overlays valv)
    attn_l_partial<<<dim3(nchunk, H_, B_), blk, 0, stream>>>(flag, q_ws, k_ws, valv_ws, maskv, part_ws, nchunk, chunk);
    attn_l_merge  <<<dim3(B_*H_*TL_/8),    blk, 0, stream>>>(part_ws, attnl_ws, nchunk);
    attn_v_kernel <<<dim3(TV_/32, H_, B_), blk, 0, stream>>>(flag, q_ws, k_ws, vall_ws, maskl, attnv_ws);

    // output projections (A internal bf16, C external)
    gemm_nt<false, true, false><<<dim3(850, 4), blk, 0, stream>>>(flag, attnv_ws, nullptr, Wov, bov, d_out, 0,        B_*TV_, VD_, E_, 1.0f);
    gemm_nt<false, true, false><<<dim3(16, 12), blk, 0, stream>>>(flag, attnl_ws, nullptr, Wol, bol, d_out, outl_off, B_*TL_, LD_, E_, 1.0f);
}

// Round 4
// 886.517 us; speedup vs baseline: 1.7443x; 1.7443x over previous
//
#include <hip/hip_runtime.h>
#include <math.h>

// ---------------------------------------------------------------------------
// RLIPv2 BiMultiHeadAttention. Round 4: MFMA everywhere except dir-l flash.
//  - prep kernels: bf16 copies of v, v+v_pos, l, all weights; fp32 biases.
//  - gemm_mfma: 128x128 tile, BK=32, mfma_f32_16x16x32_bf16, XOR-swizzled LDS.
//  - attn_v_mfma: QK^T (MFMA) -> register softmax (cross-wave LDS reduce)
//    -> P bf16 LDS round-trip -> PV (MFMA), deferred 1/L.
//  - attn_l flash + merge unchanged (VALU) - next round's target.
//  - q lives in d_out (dead before out-projections write it).
// ---------------------------------------------------------------------------

typedef unsigned short u16;
typedef unsigned int   u32;
typedef __attribute__((ext_vector_type(4))) u16 us4;
typedef __attribute__((ext_vector_type(8))) u16 us8;
typedef __attribute__((ext_vector_type(8))) short s8b;   // 8 bf16 (4 VGPRs)
typedef __attribute__((ext_vector_type(4))) float f4;    // 4 fp32 acc

#define B_   4
#define TV_  13600
#define TL_  256
#define VD_  256
#define LD_  768
#define E_   256
#define H_   8
#define HD_  32
#define PREC 36          // dir-l partial record u16 stride (72 B)

static constexpr float SCALE_  = 0.17677669529663687f;  // 32^-0.5
static constexpr float CLAMP_  = 50000.0f;
static constexpr float NEG_    = -9e15f;
static constexpr float LOG2E_  = 1.4426950408889634f;

__device__ __forceinline__ float bf2f(u16 x) {
    return __uint_as_float(((u32)x) << 16);
}
__device__ __forceinline__ u16 f2bf(float f) {           // RNE
    u32 u = __float_as_uint(f);
    u += 0x7fffu + ((u >> 16) & 1u);
    return (u16)(u >> 16);
}
template<bool F32> __device__ __forceinline__ float ld1(const void* p, size_t i) {
    if constexpr (F32) return ((const float*)p)[i];
    else               return bf2f(((const u16*)p)[i]);
}

// LDS fragment read for 32-elem-K rows with XOR quad swizzle:
// slot t of row r holds logical quad (t ^ ((r>>1)&3)).
__device__ __forceinline__ s8b frag32(const u16* base, int row, int q) {
    int slot = q ^ ((row >> 1) & 3);
    return *(const s8b*)(base + row * 32 + slot * 8);
}

// ---------------------------------------------------------------------------
__global__ void sniff_kernel(const void* __restrict__ mask, int* __restrict__ flag) {
    if (threadIdx.x == 0 && blockIdx.x == 0) {
        u32 w = *(const u32*)mask;          // mask values are exactly 1.0
        *flag = (w == 0x3F800000u) ? 1 : 0; // fp32 1.0 vs packed bf16 (1.0,1.0)
    }
}

// ---------------------------------------------------------------------------
// prep: vb = bf16(v), vqb = bf16(v + v_pos)
// ---------------------------------------------------------------------------
__global__ __launch_bounds__(256) void prep_v_kernel(
    const int* __restrict__ flag, const void* __restrict__ v,
    const void* __restrict__ vp, u16* __restrict__ vb, u16* __restrict__ vqb)
{
    const bool f32 = (*flag != 0);
    const size_t n = (size_t)B_ * TV_ * VD_;
    size_t i = ((size_t)blockIdx.x * 256 + threadIdx.x) * 4;
    const size_t stride = (size_t)gridDim.x * 256 * 4;
    for (; i < n; i += stride) {
        float a[4], b[4];
        if (f32) {
            float4 x = ((const float4*)v)[i >> 2];
            float4 y = ((const float4*)vp)[i >> 2];
            a[0]=x.x; a[1]=x.y; a[2]=x.z; a[3]=x.w;
            b[0]=y.x; b[1]=y.y; b[2]=y.z; b[3]=y.w;
        } else {
            us4 x = ((const us4*)v)[i >> 2];
            us4 y = ((const us4*)vp)[i >> 2];
            #pragma unroll
            for (int j = 0; j < 4; ++j) { a[j]=bf2f(x[j]); b[j]=bf2f(y[j]); }
        }
        us4 o1, o2;
        #pragma unroll
        for (int j = 0; j < 4; ++j) { o1[j]=f2bf(a[j]); o2[j]=f2bf(a[j]+b[j]); }
        ((us4*)vb)[i >> 2] = o1;
        ((us4*)vqb)[i >> 2] = o2;
    }
}

// prep: l + weights -> bf16; biases -> fp32
struct Seg { const void* src; void* dst; int n; int toF32; };
struct PrepArgs { Seg s[13]; };

__global__ __launch_bounds__(256) void prep_rest_kernel(
    const int* __restrict__ flag, PrepArgs args)
{
    const bool f32 = (*flag != 0);
    for (int k = 0; k < 13; ++k) {
        Seg sg = args.s[k];
        for (int j = blockIdx.x * 256 + threadIdx.x; j < sg.n;
             j += gridDim.x * 256) {
            float x = f32 ? ((const float*)sg.src)[j] : bf2f(((const u16*)sg.src)[j]);
            if (sg.toF32) ((float*)sg.dst)[j] = x;
            else          ((u16*)sg.dst)[j]   = f2bf(x);
        }
    }
}

// ---------------------------------------------------------------------------
// MFMA NT GEMM: C[m,n] = (A[m,k] . W[n,k] + bias[n]) * scale
// A, W bf16 row-major (K-contig). Tile 128x128, BK=32, 4 waves (64x64 each).
// M % 128 == 0, N % 128 == 0, K % 32 == 0.
// ---------------------------------------------------------------------------
template<bool CEXT>
__global__ __launch_bounds__(256) void gemm_mfma(
    const int* __restrict__ flag,
    const u16* __restrict__ A, const u16* __restrict__ W,
    const float* __restrict__ bias, void* __restrict__ C, size_t c_off,
    int N, int K, float scale)
{
    __shared__ u16 As[128 * 32];
    __shared__ u16 Bs[128 * 32];
    const int tid  = threadIdx.x;
    const int lane = tid & 63, wid = tid >> 6;
    const int wm = wid >> 1, wn = wid & 1;
    const size_t m0 = (size_t)blockIdx.x * 128;
    const int n0 = blockIdx.y * 128;

    const int srow = tid >> 1;          // 0..127 staging row (A and B)
    const int half = tid & 1;           // which half of the 32-K row
    const int ssw  = (srow >> 1) & 3;   // swizzle key
    const int sl0  = half * 2, sl1 = half * 2 + 1;   // LDS slots

    f4 acc[4][4];
    #pragma unroll
    for (int i = 0; i < 4; ++i)
        #pragma unroll
        for (int j = 0; j < 4; ++j) acc[i][j] = (f4){0.f, 0.f, 0.f, 0.f};

    for (int k0 = 0; k0 < K; k0 += 32) {
        {   // stage A & B tiles (slot t holds logical quad t^ssw)
            const u16* ga = A + (m0 + srow) * (size_t)K + k0;
            *(us8*)&As[srow*32 + sl0*8] = *(const us8*)(ga + (sl0 ^ ssw) * 8);
            *(us8*)&As[srow*32 + sl1*8] = *(const us8*)(ga + (sl1 ^ ssw) * 8);
            const u16* gb = W + ((size_t)(n0 + srow)) * (size_t)K + k0;
            *(us8*)&Bs[srow*32 + sl0*8] = *(const us8*)(gb + (sl0 ^ ssw) * 8);
            *(us8*)&Bs[srow*32 + sl1*8] = *(const us8*)(gb + (sl1 ^ ssw) * 8);
        }
        __syncthreads();
        s8b af[4], bf[4];
        const int q = lane >> 4;
        #pragma unroll
        for (int mt = 0; mt < 4; ++mt)
            af[mt] = frag32(As, wm*64 + mt*16 + (lane & 15), q);
        #pragma unroll
        for (int nt = 0; nt < 4; ++nt)
            bf[nt] = frag32(Bs, wn*64 + nt*16 + (lane & 15), q);
        #pragma unroll
        for (int mt = 0; mt < 4; ++mt)
            #pragma unroll
            for (int nt = 0; nt < 4; ++nt)
                acc[mt][nt] = __builtin_amdgcn_mfma_f32_16x16x32_bf16(
                    af[mt], bf[nt], acc[mt][nt], 0, 0, 0);
        __syncthreads();
    }

    // epilogue: C/D layout col=lane&15, row=(lane>>4)*4+reg
    const int q = lane >> 4;
    const bool f32out = CEXT ? (*flag != 0) : false;
    #pragma unroll
    for (int nt = 0; nt < 4; ++nt) {
        const int col = n0 + wn*64 + nt*16 + (lane & 15);
        const float bv = bias[col];
        #pragma unroll
        for (int mt = 0; mt < 4; ++mt) {
            #pragma unroll
            for (int reg = 0; reg < 4; ++reg) {
                const size_t row = m0 + wm*64 + mt*16 + q*4 + reg;
                const float val = (acc[mt][nt][reg] + bv) * scale;
                const size_t idx = c_off + row * (size_t)N + col;
                if (CEXT && f32out) ((float*)C)[idx] = val;
                else                ((u16*)C)[idx]   = f2bf(val);
            }
        }
    }
}

// ---------------------------------------------------------------------------
// Dir-v fused attention (MFMA): grid (425, H, B), 256 threads.
// Block: 32 t-rows x 256 s. Score via MFMA -> register softmax (cross-wave
// LDS reduce) -> Pbuf bf16 LDS round-trip -> PV via MFMA -> *1/L epilogue.
// ---------------------------------------------------------------------------
__global__ __launch_bounds__(256) void attn_v_mfma(
    const int* __restrict__ flag,
    const u16* __restrict__ qm, const u16* __restrict__ km,
    const u16* __restrict__ vm, const void* __restrict__ maskl,
    u16* __restrict__ outm)
{
    __shared__ u16 Qs[32 * 32];       // swizzled rows [t][k=d]
    __shared__ u16 Ks[256 * 32];      // swizzled rows [s][k=d]
    __shared__ u16 VsT[32 * 264];     // [d][s], pad 264 breaks conflicts
    __shared__ u16 Pb[32 * 264];      // [t][s] bf16 probabilities
    __shared__ float mls[256];
    __shared__ float redm[32 * 4];
    __shared__ float reds[32 * 4];

    const int tid = threadIdx.x, lane = tid & 63, wid = tid >> 6;
    const int bb = blockIdx.z, hh = blockIdx.y;
    const int t0 = blockIdx.x * 32;
    const int q  = lane >> 4;

    // ---- staging ----
    if (tid < 128) {                    // Q: 32 rows x 4 slots
        int row = tid >> 2, slot = tid & 3;
        int sw = (row >> 1) & 3;
        const u16* gp = qm + ((size_t)(bb*TV_ + t0 + row)) * E_ + hh*HD_;
        *(us8*)&Qs[row*32 + slot*8] = *(const us8*)(gp + ((slot ^ sw) * 8));
    }
    {                                   // K: thread = s row
        int s = tid, sw = (s >> 1) & 3;
        const u16* gp = km + ((size_t)(bb*TL_ + s)) * E_ + hh*HD_;
        #pragma unroll
        for (int slot = 0; slot < 4; ++slot)
            *(us8*)&Ks[s*32 + slot*8] = *(const us8*)(gp + ((slot ^ sw) * 8));
    }
    {                                   // V transposed: thread = s row
        int s = tid;
        const u16* gp = vm + ((size_t)(bb*TL_ + s)) * E_ + hh*HD_;
        #pragma unroll
        for (int d0 = 0; d0 < 32; d0 += 8) {
            us8 vv = *(const us8*)(gp + d0);
            #pragma unroll
            for (int j = 0; j < 8; ++j) VsT[(d0 + j)*264 + s] = vv[j];
        }
        float mv = (*flag) ? ((const float*)maskl)[(size_t)bb*TL_ + s]
                           : bf2f(((const u16*)maskl)[(size_t)bb*TL_ + s]);
        mls[s] = (mv == 0.0f) ? NEG_ : mv;
    }
    __syncthreads();

    // ---- score: S[32][256], wave wid owns s-slice [wid*64, wid*64+64) ----
    s8b aq[2];
    #pragma unroll
    for (int mt = 0; mt < 2; ++mt)
        aq[mt] = frag32(Qs, mt*16 + (lane & 15), q);
    f4 sacc[2][4];
    #pragma unroll
    for (int nt = 0; nt < 4; ++nt) {
        s8b bk = frag32(Ks, wid*64 + nt*16 + (lane & 15), q);
        #pragma unroll
        for (int mt = 0; mt < 2; ++mt) {
            f4 z = {0.f, 0.f, 0.f, 0.f};
            sacc[mt][nt] = __builtin_amdgcn_mfma_f32_16x16x32_bf16(aq[mt], bk, z, 0, 0, 0);
        }
    }

    // ---- clamp + mask, wave-slice max, cross-wave max ----
    const int cbase = wid * 64;
    float mcol[4];
    #pragma unroll
    for (int nt = 0; nt < 4; ++nt) mcol[nt] = mls[cbase + nt*16 + (lane & 15)];

    float z[2][4][4];
    #pragma unroll
    for (int mt = 0; mt < 2; ++mt) {
        #pragma unroll
        for (int reg = 0; reg < 4; ++reg) {
            float mx = -1e30f;
            #pragma unroll
            for (int nt = 0; nt < 4; ++nt) {
                float v = fminf(fmaxf(sacc[mt][nt][reg], -CLAMP_), CLAMP_) + mcol[nt];
                z[mt][nt][reg] = v;
                mx = fmaxf(mx, v);
            }
            mx = fmaxf(mx, __shfl_xor(mx, 1));
            mx = fmaxf(mx, __shfl_xor(mx, 2));
            mx = fmaxf(mx, __shfl_xor(mx, 4));
            mx = fmaxf(mx, __shfl_xor(mx, 8));
            if ((lane & 15) == 0) redm[(mt*16 + q*4 + reg)*4 + wid] = mx;
        }
    }
    __syncthreads();

    // ---- p = exp2(...), Pbuf write, wave-slice sum, cross-wave sum ----
    #pragma unroll
    for (int mt = 0; mt < 2; ++mt) {
        #pragma unroll
        for (int reg = 0; reg < 4; ++reg) {
            const int r = mt*16 + q*4 + reg;
            float gm = fmaxf(fmaxf(redm[r*4+0], redm[r*4+1]),
                             fmaxf(redm[r*4+2], redm[r*4+3]));
            float sum = 0.f;
            #pragma unroll
            for (int nt = 0; nt < 4; ++nt) {
                float p = exp2f((z[mt][nt][reg] - gm) * LOG2E_);
                u16 pb = f2bf(p);
                Pb[r*264 + cbase + nt*16 + (lane & 15)] = pb;
                sum += bf2f(pb);        // L consistent with bf16-rounded P
            }
            sum += __shfl_xor(sum, 1);
            sum += __shfl_xor(sum, 2);
            sum += __shfl_xor(sum, 4);
            sum += __shfl_xor(sum, 8);
            if ((lane & 15) == 0) reds[r*4 + wid] = sum;
        }
    }
    __syncthreads();

    // ---- PV: wave wid -> output tile (pm, pn) ----
    const int pm = wid >> 1, pn = wid & 1;
    f4 oacc = {0.f, 0.f, 0.f, 0.f};
    #pragma unroll
    for (int ks = 0; ks < 8; ++ks) {
        s8b pa = *(const s8b*)&Pb [(pm*16 + (lane & 15))*264 + ks*32 + q*8];
        s8b vb = *(const s8b*)&VsT[(pn*16 + (lane & 15))*264 + ks*32 + q*8];
        oacc = __builtin_amdgcn_mfma_f32_16x16x32_bf16(pa, vb, oacc, 0, 0, 0);
    }
    #pragma unroll
    for (int reg = 0; reg < 4; ++reg) {
        const int r = pm*16 + q*4 + reg;
        float L = reds[r*4+0] + reds[r*4+1] + reds[r*4+2] + reds[r*4+3];
        float o = oacc[reg] / L;
        outm[((size_t)(bb*TV_ + t0 + r)) * E_ + hh*HD_ + pn*16 + (lane & 15)] = f2bf(o);
    }
}

// ---------------------------------------------------------------------------
// Dir-l flash partials (VALU, unchanged): grid (nchunk, H, B), thread = s row.
// ---------------------------------------------------------------------------
template<bool MF32>
__device__ __forceinline__ void attn_l_body(
    const u16* qm, const u16* km, const u16* vm, const void* maskv,
    u16* part, int nchunk, int chunk,
    float (*Qc)[36], float (*Vc)[36], float* mvc)
{
    const int bb = blockIdx.z, hh = blockIdx.y, tc = blockIdx.x;
    const int tid = threadIdx.x;
    const int s = tid;

    float kr[32];
    {
        const u16* p = km + ((size_t)(bb*TL_ + s) * E_ + hh*HD_);
        #pragma unroll
        for (int d0 = 0; d0 < 32; d0 += 8) {
            us8 kv = *(const us8*)(p + d0);
            #pragma unroll
            for (int j = 0; j < 8; ++j) kr[d0+j] = bf2f(kv[j]);
        }
    }
    float m = -1e30f, lsum = 0.f;
    float acc[32];
    #pragma unroll
    for (int d = 0; d < 32; ++d) acc[d] = 0.f;

    const int c0 = tc * chunk, c1 = c0 + chunk;
    for (int t0 = c0; t0 < c1; t0 += 64) {
        const int cnt = min(64, c1 - t0);
        {
            int row = tid >> 2;
            int d0  = (tid & 3) * 8;
            if (row < cnt) {
                size_t base = (size_t)(bb*TV_ + t0 + row) * E_ + hh*HD_ + d0;
                us8 qv = *(const us8*)(qm + base);
                us8 vv = *(const us8*)(vm + base);
                #pragma unroll
                for (int j = 0; j < 8; ++j) Qc[row][d0+j] = bf2f(qv[j]);
                #pragma unroll
                for (int j = 0; j < 8; ++j) Vc[row][d0+j] = bf2f(vv[j]);
            }
            if (tid < cnt) {
                float mv = ld1<MF32>(maskv, (size_t)bb*TV_ + t0 + tid);
                mvc[tid] = (mv == 0.0f) ? NEG_ : mv;
            }
        }
        __syncthreads();
        for (int tt = 0; tt < cnt; ++tt) {
            const float4* qr = (const float4*)&Qc[tt][0];
            float sc = 0.f;
            #pragma unroll
            for (int j4 = 0; j4 < 8; ++j4) {
                float4 qv = qr[j4];
                sc += kr[j4*4+0]*qv.x + kr[j4*4+1]*qv.y
                    + kr[j4*4+2]*qv.z + kr[j4*4+3]*qv.w;
            }
            sc = fminf(fmaxf(sc, -CLAMP_), CLAMP_) + mvc[tt];
            if (sc > m) {
                float al = exp2f((m - sc) * LOG2E_);
                lsum *= al;
                #pragma unroll
                for (int d = 0; d < 32; ++d) acc[d] *= al;
                m = sc;
            }
            float p = exp2f((sc - m) * LOG2E_);
            lsum += p;
            const float4* vr = (const float4*)&Vc[tt][0];
            #pragma unroll
            for (int j4 = 0; j4 < 8; ++j4) {
                float4 vv = vr[j4];
                acc[j4*4+0] += p*vv.x; acc[j4*4+1] += p*vv.y;
                acc[j4*4+2] += p*vv.z; acc[j4*4+3] += p*vv.w;
            }
        }
        __syncthreads();
    }
    u16* rec = part + ((size_t)((bb*H_ + hh)*TL_ + s) * nchunk + tc) * PREC;
    #pragma unroll
    for (int d = 0; d < 32; ++d) rec[d] = f2bf(acc[d]);
    *(float*)(rec + 32) = m;
    *(float*)(rec + 34) = lsum;
}

__global__ __launch_bounds__(256) void attn_l_partial(
    const int* __restrict__ flag,
    const u16* __restrict__ qm, const u16* __restrict__ km,
    const u16* __restrict__ vm, const void* __restrict__ maskv,
    u16* __restrict__ part, int nchunk, int chunk)
{
    __shared__ float Qc[64][36];
    __shared__ float Vc[64][36];
    __shared__ float mvc[64];
    if (*flag) attn_l_body<true >(qm, km, vm, maskv, part, nchunk, chunk, Qc, Vc, mvc);
    else       attn_l_body<false>(qm, km, vm, maskv, part, nchunk, chunk, Qc, Vc, mvc);
}

__global__ __launch_bounds__(256) void attn_l_merge(
    const u16* __restrict__ part, u16* __restrict__ outm, int nchunk)
{
    const int R = blockIdx.x * 8 + (threadIdx.x >> 5);
    const int d = threadIdx.x & 31;
    const u16* rec0 = part + (size_t)R * nchunk * PREC;
    float m = -1e30f;
    for (int c = 0; c < nchunk; ++c)
        m = fmaxf(m, *(const float*)(rec0 + c*PREC + 32));
    float L = 0.f, o = 0.f;
    for (int c = 0; c < nchunk; ++c) {
        float mc = *(const float*)(rec0 + c*PREC + 32);
        float lc = *(const float*)(rec0 + c*PREC + 34);
        float w  = exp2f((mc - m) * LOG2E_);
        L += lc * w;
        o += bf2f(rec0[c*PREC + d]) * w;
    }
    o /= L;
    const int bb = R >> 11, hh = (R >> 8) & 7, ss = R & 255;
    outm[(size_t)(bb*TL_ + ss) * E_ + hh*HD_ + d] = f2bf(o);
}

// ---------------------------------------------------------------------------
extern "C" void kernel_launch(void* const* d_in, const int* in_sizes, int n_in,
                              void* d_out, int out_size, void* d_ws, size_t ws_size,
                              hipStream_t stream)
{
    const void* v     = d_in[0];
    const void* l     = d_in[1];
    const void* vpos  = d_in[2];
    const void* maskv = d_in[3];
    const void* maskl = d_in[4];
    const void* Wq  = d_in[5];   const void* bq  = d_in[6];
    const void* Wk  = d_in[7];   const void* bk  = d_in[8];
    const void* Wvv = d_in[9];   const void* bvv = d_in[10];
    const void* Wvl = d_in[11];  const void* bvl = d_in[12];
    const void* Wov = d_in[13];  const void* bov = d_in[14];
    const void* Wol = d_in[15];  const void* bol = d_in[16];

    const size_t BIG   = (size_t)B_*TV_*E_*2;     // 27,852,800 B
    const size_t TLBUF = (size_t)B_*TL_*E_*2;     // 524,288 B
    const size_t LBUF  = (size_t)B_*TL_*LD_*2;    // 1,572,864 B
    auto part_bytes = [](int nc) { return (size_t)B_*H_*TL_ * (size_t)nc * (PREC*2); };

    // adaptive nchunk for dir-l (q always lives in d_out)
    const size_t fixed = 512 + 2*(BIG+256) + (LBUF+256) + 3*(TLBUF+256)
                       + (131072+256)*3 + (393216+256)*3 + (8192+256);
    int nchunk = 16;
    while (nchunk > 1 && fixed + part_bytes(nchunk) + 256 > ws_size) nchunk >>= 1;
    const int chunk = TV_ / nchunk;

    char* ws = (char*)d_ws;
    size_t off = 0;
    auto carve = [&](size_t bytes) -> char* {
        char* p = ws + off;
        off += (bytes + 255) & ~(size_t)255;
        return p;
    };
    int*   flag    = (int*)carve(512);
    u16*   slot1   = (u16*)carve(BIG);     // vb -> attnv
    u16*   slot2   = (u16*)carve(BIG);     // vqb -> valv
    u16*   lb      = (u16*)carve(LBUF);
    u16*   k_ws    = (u16*)carve(TLBUF);
    u16*   vall_ws = (u16*)carve(TLBUF);
    u16*   attnl_ws= (u16*)carve(TLBUF);
    u16*   wqb     = (u16*)carve(131072);
    u16*   wkb     = (u16*)carve(393216);
    u16*   wvvb    = (u16*)carve(131072);
    u16*   wvlb    = (u16*)carve(393216);
    u16*   wovb    = (u16*)carve(131072);
    u16*   wolb    = (u16*)carve(393216);
    float* biasf   = (float*)carve(8192);  // 2048 floats
    u16*   part_ws = (u16*)carve(part_bytes(nchunk));

    u16* vb    = slot1;
    u16* vqb   = slot2;
    u16* valv  = slot2;    // born after vqb dies (G1 before G2)
    u16* attnv = slot1;    // born after vb dies (G2 before attn_v)
    u16* q_ws  = (u16*)d_out;  // dead before out-projections write d_out

    float* bqf  = biasf;        float* bkf  = biasf + 256;
    float* bvvf = biasf + 512;  float* bvlf = biasf + 768;
    float* bovf = biasf + 1024; float* bolf = biasf + 1280;

    const dim3 blk(256);
    const size_t outl_off = (size_t)B_*TV_*VD_;

    sniff_kernel<<<1, 64, 0, stream>>>(maskv, flag);

    prep_v_kernel<<<2048, blk, 0, stream>>>(flag, v, vpos, vb, vqb);
    PrepArgs pa;
    pa.s[0]  = { l,   lb,   B_*TL_*LD_, 0 };
    pa.s[1]  = { Wq,  wqb,  E_*VD_,     0 };
    pa.s[2]  = { Wk,  wkb,  E_*LD_,     0 };
    pa.s[3]  = { Wvv, wvvb, E_*VD_,     0 };
    pa.s[4]  = { Wvl, wvlb, E_*LD_,     0 };
    pa.s[5]  = { Wov, wovb, VD_*E_,     0 };
    pa.s[6]  = { Wol, wolb, LD_*E_,     0 };
    pa.s[7]  = { bq,  bqf,  E_,  1 };
    pa.s[8]  = { bk,  bkf,  E_,  1 };
    pa.s[9]  = { bvv, bvvf, E_,  1 };
    pa.s[10] = { bvl, bvlf, E_,  1 };
    pa.s[11] = { bov, bovf, VD_, 1 };
    pa.s[12] = { bol, bolf, LD_, 1 };
    prep_rest_kernel<<<256, blk, 0, stream>>>(flag, pa);

    // projections (MFMA)
    gemm_mfma<false><<<dim3(425, 2), blk, 0, stream>>>(flag, vqb, wqb,  bqf,  q_ws,    0, E_, VD_, SCALE_);
    gemm_mfma<false><<<dim3(425, 2), blk, 0, stream>>>(flag, vb,  wvvb, bvvf, valv,    0, E_, VD_, 1.0f);
    gemm_mfma<false><<<dim3(8,   2), blk, 0, stream>>>(flag, lb,  wkb,  bkf,  k_ws,    0, E_, LD_, 1.0f);
    gemm_mfma<false><<<dim3(8,   2), blk, 0, stream>>>(flag, lb,  wvlb, bvlf, vall_ws, 0, E_, LD_, 1.0f);

    // dir-l first (consumes valv), then dir-v (attnv overlays vb)
    attn_l_partial<<<dim3(nchunk, H_, B_), blk, 0, stream>>>(flag, q_ws, k_ws, valv, maskv, part_ws, nchunk, chunk);
    attn_l_merge  <<<dim3(B_*H_*TL_/8),    blk, 0, stream>>>(part_ws, attnl_ws, nchunk);
    attn_v_mfma   <<<dim3(TV_/32, H_, B_), blk, 0, stream>>>(flag, q_ws, k_ws, vall_ws, maskl, attnv);

    // output projections (MFMA, external dtype epilogue)
    gemm_mfma<true><<<dim3(425, 2), blk, 0, stream>>>(flag, attnv,    wovb, bovf, d_out, 0,        VD_, E_, 1.0f);
    gemm_mfma<true><<<dim3(8,   6), blk, 0, stream>>>(flag, attnl_ws, wolb, bolf, d_out, outl_off, LD_, E_, 1.0f);
}

// Round 5
// 712.155 us; speedup vs baseline: 2.1714x; 1.2448x over previous
//
#include <hip/hip_runtime.h>
#include <math.h>

// ---------------------------------------------------------------------------
// RLIPv2 BiMultiHeadAttention. Round 5: dir-l flash moved to MFMA.
//  - attn_l_mfma: per (b,h,chunk) block: K persistent in A-frags; per 32-t
//    step: S^T = K.Q^T (MFMA) -> online softmax in C-frag registers ->
//    P bf16 LDS (pad-40 rows, wave-private) -> PV (MFMA). Partial records
//    (32 bf16 acc + fp32 m,l) unchanged; merge kernel unchanged.
//  - everything else identical to round 4 (all-MFMA projections, attn_v).
// ---------------------------------------------------------------------------

typedef unsigned short u16;
typedef unsigned int   u32;
typedef __attribute__((ext_vector_type(4))) u16 us4;
typedef __attribute__((ext_vector_type(8))) u16 us8;
typedef __attribute__((ext_vector_type(8))) short s8b;   // 8 bf16 (4 VGPRs)
typedef __attribute__((ext_vector_type(4))) float f4;    // 4 fp32 acc

#define B_   4
#define TV_  13600
#define TL_  256
#define VD_  256
#define LD_  768
#define E_   256
#define H_   8
#define HD_  32
#define PREC 36          // dir-l partial record u16 stride (72 B)

static constexpr float SCALE_  = 0.17677669529663687f;  // 32^-0.5
static constexpr float CLAMP_  = 50000.0f;
static constexpr float NEG_    = -9e15f;
static constexpr float LOG2E_  = 1.4426950408889634f;

__device__ __forceinline__ float bf2f(u16 x) {
    return __uint_as_float(((u32)x) << 16);
}
__device__ __forceinline__ u16 f2bf(float f) {           // RNE
    u32 u = __float_as_uint(f);
    u += 0x7fffu + ((u >> 16) & 1u);
    return (u16)(u >> 16);
}

// LDS fragment read for 32-elem-K rows with XOR quad swizzle:
// slot t of row r holds logical quad (t ^ ((r>>1)&3)).
__device__ __forceinline__ s8b frag32(const u16* base, int row, int q) {
    int slot = q ^ ((row >> 1) & 3);
    return *(const s8b*)(base + row * 32 + slot * 8);
}

// ---------------------------------------------------------------------------
__global__ void sniff_kernel(const void* __restrict__ mask, int* __restrict__ flag) {
    if (threadIdx.x == 0 && blockIdx.x == 0) {
        u32 w = *(const u32*)mask;          // mask values are exactly 1.0
        *flag = (w == 0x3F800000u) ? 1 : 0; // fp32 1.0 vs packed bf16 (1.0,1.0)
    }
}

// ---------------------------------------------------------------------------
// prep: vb = bf16(v), vqb = bf16(v + v_pos)
// ---------------------------------------------------------------------------
__global__ __launch_bounds__(256) void prep_v_kernel(
    const int* __restrict__ flag, const void* __restrict__ v,
    const void* __restrict__ vp, u16* __restrict__ vb, u16* __restrict__ vqb)
{
    const bool f32 = (*flag != 0);
    const size_t n = (size_t)B_ * TV_ * VD_;
    size_t i = ((size_t)blockIdx.x * 256 + threadIdx.x) * 4;
    const size_t stride = (size_t)gridDim.x * 256 * 4;
    for (; i < n; i += stride) {
        float a[4], b[4];
        if (f32) {
            float4 x = ((const float4*)v)[i >> 2];
            float4 y = ((const float4*)vp)[i >> 2];
            a[0]=x.x; a[1]=x.y; a[2]=x.z; a[3]=x.w;
            b[0]=y.x; b[1]=y.y; b[2]=y.z; b[3]=y.w;
        } else {
            us4 x = ((const us4*)v)[i >> 2];
            us4 y = ((const us4*)vp)[i >> 2];
            #pragma unroll
            for (int j = 0; j < 4; ++j) { a[j]=bf2f(x[j]); b[j]=bf2f(y[j]); }
        }
        us4 o1, o2;
        #pragma unroll
        for (int j = 0; j < 4; ++j) { o1[j]=f2bf(a[j]); o2[j]=f2bf(a[j]+b[j]); }
        ((us4*)vb)[i >> 2] = o1;
        ((us4*)vqb)[i >> 2] = o2;
    }
}

// prep: l + weights -> bf16; biases -> fp32
struct Seg { const void* src; void* dst; int n; int toF32; };
struct PrepArgs { Seg s[13]; };

__global__ __launch_bounds__(256) void prep_rest_kernel(
    const int* __restrict__ flag, PrepArgs args)
{
    const bool f32 = (*flag != 0);
    for (int k = 0; k < 13; ++k) {
        Seg sg = args.s[k];
        for (int j = blockIdx.x * 256 + threadIdx.x; j < sg.n;
             j += gridDim.x * 256) {
            float x = f32 ? ((const float*)sg.src)[j] : bf2f(((const u16*)sg.src)[j]);
            if (sg.toF32) ((float*)sg.dst)[j] = x;
            else          ((u16*)sg.dst)[j]   = f2bf(x);
        }
    }
}

// ---------------------------------------------------------------------------
// MFMA NT GEMM: C[m,n] = (A[m,k] . W[n,k] + bias[n]) * scale
// Tile 128x128, BK=32, 4 waves (64x64 each). M%128==0, N%128==0, K%32==0.
// ---------------------------------------------------------------------------
template<bool CEXT>
__global__ __launch_bounds__(256) void gemm_mfma(
    const int* __restrict__ flag,
    const u16* __restrict__ A, const u16* __restrict__ W,
    const float* __restrict__ bias, void* __restrict__ C, size_t c_off,
    int N, int K, float scale)
{
    __shared__ u16 As[128 * 32];
    __shared__ u16 Bs[128 * 32];
    const int tid  = threadIdx.x;
    const int lane = tid & 63, wid = tid >> 6;
    const int wm = wid >> 1, wn = wid & 1;
    const size_t m0 = (size_t)blockIdx.x * 128;
    const int n0 = blockIdx.y * 128;

    const int srow = tid >> 1;
    const int half = tid & 1;
    const int ssw  = (srow >> 1) & 3;
    const int sl0  = half * 2, sl1 = half * 2 + 1;

    f4 acc[4][4];
    #pragma unroll
    for (int i = 0; i < 4; ++i)
        #pragma unroll
        for (int j = 0; j < 4; ++j) acc[i][j] = (f4){0.f, 0.f, 0.f, 0.f};

    for (int k0 = 0; k0 < K; k0 += 32) {
        {
            const u16* ga = A + (m0 + srow) * (size_t)K + k0;
            *(us8*)&As[srow*32 + sl0*8] = *(const us8*)(ga + (sl0 ^ ssw) * 8);
            *(us8*)&As[srow*32 + sl1*8] = *(const us8*)(ga + (sl1 ^ ssw) * 8);
            const u16* gb = W + ((size_t)(n0 + srow)) * (size_t)K + k0;
            *(us8*)&Bs[srow*32 + sl0*8] = *(const us8*)(gb + (sl0 ^ ssw) * 8);
            *(us8*)&Bs[srow*32 + sl1*8] = *(const us8*)(gb + (sl1 ^ ssw) * 8);
        }
        __syncthreads();
        s8b af[4], bf[4];
        const int q = lane >> 4;
        #pragma unroll
        for (int mt = 0; mt < 4; ++mt)
            af[mt] = frag32(As, wm*64 + mt*16 + (lane & 15), q);
        #pragma unroll
        for (int nt = 0; nt < 4; ++nt)
            bf[nt] = frag32(Bs, wn*64 + nt*16 + (lane & 15), q);
        #pragma unroll
        for (int mt = 0; mt < 4; ++mt)
            #pragma unroll
            for (int nt = 0; nt < 4; ++nt)
                acc[mt][nt] = __builtin_amdgcn_mfma_f32_16x16x32_bf16(
                    af[mt], bf[nt], acc[mt][nt], 0, 0, 0);
        __syncthreads();
    }

    const int q = lane >> 4;
    const bool f32out = CEXT ? (*flag != 0) : false;
    #pragma unroll
    for (int nt = 0; nt < 4; ++nt) {
        const int col = n0 + wn*64 + nt*16 + (lane & 15);
        const float bv = bias[col];
        #pragma unroll
        for (int mt = 0; mt < 4; ++mt) {
            #pragma unroll
            for (int reg = 0; reg < 4; ++reg) {
                const size_t row = m0 + wm*64 + mt*16 + q*4 + reg;
                const float val = (acc[mt][nt][reg] + bv) * scale;
                const size_t idx = c_off + row * (size_t)N + col;
                if (CEXT && f32out) ((float*)C)[idx] = val;
                else                ((u16*)C)[idx]   = f2bf(val);
            }
        }
    }
}

// ---------------------------------------------------------------------------
// Dir-v fused attention (MFMA): grid (425, H, B), 256 threads.
// ---------------------------------------------------------------------------
__global__ __launch_bounds__(256) void attn_v_mfma(
    const int* __restrict__ flag,
    const u16* __restrict__ qm, const u16* __restrict__ km,
    const u16* __restrict__ vm, const void* __restrict__ maskl,
    u16* __restrict__ outm)
{
    __shared__ u16 Qs[32 * 32];
    __shared__ u16 Ks[256 * 32];
    __shared__ u16 VsT[32 * 264];
    __shared__ u16 Pb[32 * 264];
    __shared__ float mls[256];
    __shared__ float redm[32 * 4];
    __shared__ float reds[32 * 4];

    const int tid = threadIdx.x, lane = tid & 63, wid = tid >> 6;
    const int bb = blockIdx.z, hh = blockIdx.y;
    const int t0 = blockIdx.x * 32;
    const int q  = lane >> 4;

    if (tid < 128) {
        int row = tid >> 2, slot = tid & 3;
        int sw = (row >> 1) & 3;
        const u16* gp = qm + ((size_t)(bb*TV_ + t0 + row)) * E_ + hh*HD_;
        *(us8*)&Qs[row*32 + slot*8] = *(const us8*)(gp + ((slot ^ sw) * 8));
    }
    {
        int s = tid, sw = (s >> 1) & 3;
        const u16* gp = km + ((size_t)(bb*TL_ + s)) * E_ + hh*HD_;
        #pragma unroll
        for (int slot = 0; slot < 4; ++slot)
            *(us8*)&Ks[s*32 + slot*8] = *(const us8*)(gp + ((slot ^ sw) * 8));
    }
    {
        int s = tid;
        const u16* gp = vm + ((size_t)(bb*TL_ + s)) * E_ + hh*HD_;
        #pragma unroll
        for (int d0 = 0; d0 < 32; d0 += 8) {
            us8 vv = *(const us8*)(gp + d0);
            #pragma unroll
            for (int j = 0; j < 8; ++j) VsT[(d0 + j)*264 + s] = vv[j];
        }
        float mv = (*flag) ? ((const float*)maskl)[(size_t)bb*TL_ + s]
                           : bf2f(((const u16*)maskl)[(size_t)bb*TL_ + s]);
        mls[s] = (mv == 0.0f) ? NEG_ : mv;
    }
    __syncthreads();

    s8b aq[2];
    #pragma unroll
    for (int mt = 0; mt < 2; ++mt)
        aq[mt] = frag32(Qs, mt*16 + (lane & 15), q);
    f4 sacc[2][4];
    #pragma unroll
    for (int nt = 0; nt < 4; ++nt) {
        s8b bk = frag32(Ks, wid*64 + nt*16 + (lane & 15), q);
        #pragma unroll
        for (int mt = 0; mt < 2; ++mt) {
            f4 z = {0.f, 0.f, 0.f, 0.f};
            sacc[mt][nt] = __builtin_amdgcn_mfma_f32_16x16x32_bf16(aq[mt], bk, z, 0, 0, 0);
        }
    }

    const int cbase = wid * 64;
    float mcol[4];
    #pragma unroll
    for (int nt = 0; nt < 4; ++nt) mcol[nt] = mls[cbase + nt*16 + (lane & 15)];

    float z[2][4][4];
    #pragma unroll
    for (int mt = 0; mt < 2; ++mt) {
        #pragma unroll
        for (int reg = 0; reg < 4; ++reg) {
            float mx = -1e30f;
            #pragma unroll
            for (int nt = 0; nt < 4; ++nt) {
                float v = fminf(fmaxf(sacc[mt][nt][reg], -CLAMP_), CLAMP_) + mcol[nt];
                z[mt][nt][reg] = v;
                mx = fmaxf(mx, v);
            }
            mx = fmaxf(mx, __shfl_xor(mx, 1));
            mx = fmaxf(mx, __shfl_xor(mx, 2));
            mx = fmaxf(mx, __shfl_xor(mx, 4));
            mx = fmaxf(mx, __shfl_xor(mx, 8));
            if ((lane & 15) == 0) redm[(mt*16 + q*4 + reg)*4 + wid] = mx;
        }
    }
    __syncthreads();

    #pragma unroll
    for (int mt = 0; mt < 2; ++mt) {
        #pragma unroll
        for (int reg = 0; reg < 4; ++reg) {
            const int r = mt*16 + q*4 + reg;
            float gm = fmaxf(fmaxf(redm[r*4+0], redm[r*4+1]),
                             fmaxf(redm[r*4+2], redm[r*4+3]));
            float sum = 0.f;
            #pragma unroll
            for (int nt = 0; nt < 4; ++nt) {
                float p = exp2f((z[mt][nt][reg] - gm) * LOG2E_);
                u16 pb = f2bf(p);
                Pb[r*264 + cbase + nt*16 + (lane & 15)] = pb;
                sum += bf2f(pb);
            }
            sum += __shfl_xor(sum, 1);
            sum += __shfl_xor(sum, 2);
            sum += __shfl_xor(sum, 4);
            sum += __shfl_xor(sum, 8);
            if ((lane & 15) == 0) reds[r*4 + wid] = sum;
        }
    }
    __syncthreads();

    const int pm = wid >> 1, pn = wid & 1;
    f4 oacc = {0.f, 0.f, 0.f, 0.f};
    #pragma unroll
    for (int ks = 0; ks < 8; ++ks) {
        s8b pa = *(const s8b*)&Pb [(pm*16 + (lane & 15))*264 + ks*32 + q*8];
        s8b vb = *(const s8b*)&VsT[(pn*16 + (lane & 15))*264 + ks*32 + q*8];
        oacc = __builtin_amdgcn_mfma_f32_16x16x32_bf16(pa, vb, oacc, 0, 0, 0);
    }
    #pragma unroll
    for (int reg = 0; reg < 4; ++reg) {
        const int r = pm*16 + q*4 + reg;
        float L = reds[r*4+0] + reds[r*4+1] + reds[r*4+2] + reds[r*4+3];
        float o = oacc[reg] / L;
        outm[((size_t)(bb*TV_ + t0 + r)) * E_ + hh*HD_ + pn*16 + (lane & 15)] = f2bf(o);
    }
}

// ---------------------------------------------------------------------------
// Dir-l flash partials (MFMA): grid (nchunk, H, B), 256 threads.
// Block: all 256 s-rows x one t-chunk (multiple of 32). K persistent A-frags;
// per 32-t step: S^T=K.Q^T -> register online softmax -> P LDS -> PV MFMA.
// ---------------------------------------------------------------------------
__global__ __launch_bounds__(256) void attn_l_mfma(
    const int* __restrict__ flag,
    const u16* __restrict__ qm, const u16* __restrict__ km,
    const u16* __restrict__ vm, const void* __restrict__ maskv,
    u16* __restrict__ part, int nchunk, int chunk)
{
    __shared__ u16 smem0[256 * 40];   // K staging (first 256*32), then Pb rows pad 40
    __shared__ u16 Qs[32 * 32];       // per-step Q tile, swizzled rows [t][d]
    __shared__ u16 VTs[32 * 32];      // per-step V^T, swizzled rows [d][t]
    __shared__ float mvs[32];

    const int tid = threadIdx.x, lane = tid & 63, wid = tid >> 6;
    const int bb = blockIdx.z, hh = blockIdx.y, tc = blockIdx.x;
    const int q = lane >> 4;
    const bool f32m = (*flag != 0);

    // stage K (each wave stages exactly its own 64 s-rows)
    {
        int s = tid, sw = (s >> 1) & 3;
        const u16* gp = km + ((size_t)(bb*TL_ + s)) * E_ + hh*HD_;
        #pragma unroll
        for (int slot = 0; slot < 4; ++slot)
            *(us8*)&smem0[s*32 + slot*8] = *(const us8*)(gp + ((slot ^ sw) * 8));
    }
    __syncthreads();
    s8b af[4];
    #pragma unroll
    for (int mt = 0; mt < 4; ++mt)
        af[mt] = frag32(smem0, wid*64 + mt*16 + (lane & 15), q);
    __syncthreads();   // smem0 now free -> becomes Pb

    float m_s[4][4], l_s[4][4];
    f4 oacc[4][2];
    #pragma unroll
    for (int mt = 0; mt < 4; ++mt) {
        #pragma unroll
        for (int reg = 0; reg < 4; ++reg) { m_s[mt][reg] = -1e30f; l_s[mt][reg] = 0.f; }
        oacc[mt][0] = (f4){0.f,0.f,0.f,0.f};
        oacc[mt][1] = (f4){0.f,0.f,0.f,0.f};
    }

    const int nstep = chunk >> 5;
    for (int step = 0; step < nstep; ++step) {
        const int t0 = tc * chunk + step * 32;
        // ---- stage Q tile (swizzled rows [t][d]) + V^T tile + mask ----
        if (tid < 128) {
            int row = tid >> 2, slot = tid & 3;
            int sw = (row >> 1) & 3;
            const u16* gp = qm + ((size_t)(bb*TV_ + t0 + row)) * E_ + hh*HD_;
            *(us8*)&Qs[row*32 + slot*8] = *(const us8*)(gp + ((slot ^ sw) * 8));

            int trow = tid >> 2;
            int d0 = (tid & 3) * 8;
            us8 vv = *(const us8*)(vm + ((size_t)(bb*TV_ + t0 + trow)) * E_ + hh*HD_ + d0);
            #pragma unroll
            for (int j = 0; j < 8; ++j) {
                int d = d0 + j;
                VTs[d*32 + (((trow >> 3) ^ ((d >> 1) & 3)) * 8) + (trow & 7)] = vv[j];
            }
        } else if (tid < 160) {
            int t = tid - 128;
            float mv = f32m ? ((const float*)maskv)[(size_t)bb*TV_ + t0 + t]
                            : bf2f(((const u16*)maskv)[(size_t)bb*TV_ + t0 + t]);
            mvs[t] = (mv == 0.0f) ? NEG_ : mv;
        }
        __syncthreads();

        // ---- scores: S^T[s 64/wave][t 32] ----
        s8b bq[2];
        bq[0] = frag32(Qs, (lane & 15), q);
        bq[1] = frag32(Qs, 16 + (lane & 15), q);
        f4 sacc[4][2];
        #pragma unroll
        for (int mt = 0; mt < 4; ++mt) {
            #pragma unroll
            for (int nt = 0; nt < 2; ++nt) {
                f4 zz = {0.f, 0.f, 0.f, 0.f};
                sacc[mt][nt] = __builtin_amdgcn_mfma_f32_16x16x32_bf16(af[mt], bq[nt], zz, 0, 0, 0);
            }
        }

        // ---- online softmax in C-layout (row s = q*4+reg) ----
        const float mv0 = mvs[lane & 15];
        const float mv1 = mvs[16 + (lane & 15)];
        #pragma unroll
        for (int mt = 0; mt < 4; ++mt) {
            #pragma unroll
            for (int reg = 0; reg < 4; ++reg) {
                float v0 = fminf(fmaxf(sacc[mt][0][reg], -CLAMP_), CLAMP_) + mv0;
                float v1 = fminf(fmaxf(sacc[mt][1][reg], -CLAMP_), CLAMP_) + mv1;
                float mx = fmaxf(v0, v1);
                mx = fmaxf(mx, __shfl_xor(mx, 1));
                mx = fmaxf(mx, __shfl_xor(mx, 2));
                mx = fmaxf(mx, __shfl_xor(mx, 4));
                mx = fmaxf(mx, __shfl_xor(mx, 8));
                float mo = m_s[mt][reg];
                float nm = fmaxf(mo, mx);
                float al = exp2f((mo - nm) * LOG2E_);
                u16 p0 = f2bf(exp2f((v0 - nm) * LOG2E_));
                u16 p1 = f2bf(exp2f((v1 - nm) * LOG2E_));
                float ps = bf2f(p0) + bf2f(p1);
                ps += __shfl_xor(ps, 1);
                ps += __shfl_xor(ps, 2);
                ps += __shfl_xor(ps, 4);
                ps += __shfl_xor(ps, 8);
                l_s[mt][reg] = l_s[mt][reg] * al + ps;
                m_s[mt][reg] = nm;
                oacc[mt][0][reg] *= al;
                oacc[mt][1][reg] *= al;
                const int srow = wid*64 + mt*16 + q*4 + reg;
                smem0[srow*40 + (lane & 15)]      = p0;   // Pb, wave-private rows
                smem0[srow*40 + 16 + (lane & 15)] = p1;
            }
        }

        // ---- PV: oacc[s 64][d 32] += P.V ----
        s8b bv[2];
        bv[0] = frag32(VTs, (lane & 15), q);
        bv[1] = frag32(VTs, 16 + (lane & 15), q);
        #pragma unroll
        for (int mt = 0; mt < 4; ++mt) {
            s8b pa = *(const s8b*)&smem0[(wid*64 + mt*16 + (lane & 15))*40 + q*8];
            #pragma unroll
            for (int nt = 0; nt < 2; ++nt)
                oacc[mt][nt] = __builtin_amdgcn_mfma_f32_16x16x32_bf16(pa, bv[nt], oacc[mt][nt], 0, 0, 0);
        }
        __syncthreads();   // before next step's staging overwrites Qs/VTs
    }

    // ---- epilogue: write partial records ----
    #pragma unroll
    for (int mt = 0; mt < 4; ++mt) {
        #pragma unroll
        for (int reg = 0; reg < 4; ++reg) {
            const int s = wid*64 + mt*16 + q*4 + reg;
            u16* rec = part + ((size_t)((bb*H_ + hh)*TL_ + s) * nchunk + tc) * PREC;
            rec[lane & 15]        = f2bf(oacc[mt][0][reg]);
            rec[16 + (lane & 15)] = f2bf(oacc[mt][1][reg]);
            if ((lane & 15) == 0) {
                *(float*)(rec + 32) = m_s[mt][reg];
                *(float*)(rec + 34) = l_s[mt][reg];
            }
        }
    }
}

// Merge partials per (b,h,s) row. grid 1024 x 256 (8 rows/block, 32 lanes/row).
__global__ __launch_bounds__(256) void attn_l_merge(
    const u16* __restrict__ part, u16* __restrict__ outm, int nchunk)
{
    const int R = blockIdx.x * 8 + (threadIdx.x >> 5);
    const int d = threadIdx.x & 31;
    const u16* rec0 = part + (size_t)R * nchunk * PREC;
    float m = -1e30f;
    for (int c = 0; c < nchunk; ++c)
        m = fmaxf(m, *(const float*)(rec0 + c*PREC + 32));
    float L = 0.f, o = 0.f;
    for (int c = 0; c < nchunk; ++c) {
        float mc = *(const float*)(rec0 + c*PREC + 32);
        float lc = *(const float*)(rec0 + c*PREC + 34);
        float w  = exp2f((mc - m) * LOG2E_);
        L += lc * w;
        o += bf2f(rec0[c*PREC + d]) * w;
    }
    o /= L;
    const int bb = R >> 11, hh = (R >> 8) & 7, ss = R & 255;
    outm[(size_t)(bb*TL_ + ss) * E_ + hh*HD_ + d] = f2bf(o);
}

// ---------------------------------------------------------------------------
extern "C" void kernel_launch(void* const* d_in, const int* in_sizes, int n_in,
                              void* d_out, int out_size, void* d_ws, size_t ws_size,
                              hipStream_t stream)
{
    const void* v     = d_in[0];
    const void* l     = d_in[1];
    const void* vpos  = d_in[2];
    const void* maskv = d_in[3];
    const void* maskl = d_in[4];
    const void* Wq  = d_in[5];   const void* bq  = d_in[6];
    const void* Wk  = d_in[7];   const void* bk  = d_in[8];
    const void* Wvv = d_in[9];   const void* bvv = d_in[10];
    const void* Wvl = d_in[11];  const void* bvl = d_in[12];
    const void* Wov = d_in[13];  const void* bov = d_in[14];
    const void* Wol = d_in[15];  const void* bol = d_in[16];

    const size_t BIG   = (size_t)B_*TV_*E_*2;     // 27,852,800 B
    const size_t TLBUF = (size_t)B_*TL_*E_*2;     // 524,288 B
    const size_t LBUF  = (size_t)B_*TL_*LD_*2;    // 1,572,864 B
    auto part_bytes = [](int nc) { return (size_t)B_*H_*TL_ * (size_t)nc * (PREC*2); };

    // chunk must be a multiple of 32: 13600 = 25*544 = 17*800 = 5*2720
    const size_t fixed = 512 + 2*(BIG+256) + (LBUF+256) + 3*(TLBUF+256)
                       + (131072+256)*3 + (393216+256)*3 + (8192+256);
    const int cand[3] = {25, 17, 5};
    int nchunk = 5;
    for (int i = 0; i < 3; ++i)
        if (fixed + part_bytes(cand[i]) + 256 <= ws_size) { nchunk = cand[i]; break; }
    const int chunk = TV_ / nchunk;

    char* ws = (char*)d_ws;
    size_t off = 0;
    auto carve = [&](size_t bytes) -> char* {
        char* p = ws + off;
        off += (bytes + 255) & ~(size_t)255;
        return p;
    };
    int*   flag    = (int*)carve(512);
    u16*   slot1   = (u16*)carve(BIG);     // vb -> attnv
    u16*   slot2   = (u16*)carve(BIG);     // vqb -> valv
    u16*   lb      = (u16*)carve(LBUF);
    u16*   k_ws    = (u16*)carve(TLBUF);
    u16*   vall_ws = (u16*)carve(TLBUF);
    u16*   attnl_ws= (u16*)carve(TLBUF);
    u16*   wqb     = (u16*)carve(131072);
    u16*   wkb     = (u16*)carve(393216);
    u16*   wvvb    = (u16*)carve(131072);
    u16*   wvlb    = (u16*)carve(393216);
    u16*   wovb    = (u16*)carve(131072);
    u16*   wolb    = (u16*)carve(393216);
    float* biasf   = (float*)carve(8192);  // 2048 floats
    u16*   part_ws = (u16*)carve(part_bytes(nchunk));

    u16* vb    = slot1;
    u16* vqb   = slot2;
    u16* valv  = slot2;    // born after vqb dies (G1 before G2)
    u16* attnv = slot1;    // born after vb dies (G2 before attn_v)
    u16* q_ws  = (u16*)d_out;  // dead before out-projections write d_out

    float* bqf  = biasf;        float* bkf  = biasf + 256;
    float* bvvf = biasf + 512;  float* bvlf = biasf + 768;
    float* bovf = biasf + 1024; float* bolf = biasf + 1280;

    const dim3 blk(256);
    const size_t outl_off = (size_t)B_*TV_*VD_;

    sniff_kernel<<<1, 64, 0, stream>>>(maskv, flag);

    prep_v_kernel<<<2048, blk, 0, stream>>>(flag, v, vpos, vb, vqb);
    PrepArgs pa;
    pa.s[0]  = { l,   lb,   B_*TL_*LD_, 0 };
    pa.s[1]  = { Wq,  wqb,  E_*VD_,     0 };
    pa.s[2]  = { Wk,  wkb,  E_*LD_,     0 };
    pa.s[3]  = { Wvv, wvvb, E_*VD_,     0 };
    pa.s[4]  = { Wvl, wvlb, E_*LD_,     0 };
    pa.s[5]  = { Wov, wovb, VD_*E_,     0 };
    pa.s[6]  = { Wol, wolb, LD_*E_,     0 };
    pa.s[7]  = { bq,  bqf,  E_,  1 };
    pa.s[8]  = { bk,  bkf,  E_,  1 };
    pa.s[9]  = { bvv, bvvf, E_,  1 };
    pa.s[10] = { bvl, bvlf, E_,  1 };
    pa.s[11] = { bov, bovf, VD_, 1 };
    pa.s[12] = { bol, bolf, LD_, 1 };
    prep_rest_kernel<<<256, blk, 0, stream>>>(flag, pa);

    // projections (MFMA)
    gemm_mfma<false><<<dim3(425, 2), blk, 0, stream>>>(flag, vqb, wqb,  bqf,  q_ws,    0, E_, VD_, SCALE_);
    gemm_mfma<false><<<dim3(425, 2), blk, 0, stream>>>(flag, vb,  wvvb, bvvf, valv,    0, E_, VD_, 1.0f);
    gemm_mfma<false><<<dim3(8,   2), blk, 0, stream>>>(flag, lb,  wkb,  bkf,  k_ws,    0, E_, LD_, 1.0f);
    gemm_mfma<false><<<dim3(8,   2), blk, 0, stream>>>(flag, lb,  wvlb, bvlf, vall_ws, 0, E_, LD_, 1.0f);

    // dir-l first (consumes valv), then dir-v (attnv overlays vb)
    attn_l_mfma <<<dim3(nchunk, H_, B_), blk, 0, stream>>>(flag, q_ws, k_ws, valv, maskv, part_ws, nchunk, chunk);
    attn_l_merge<<<dim3(B_*H_*TL_/8),    blk, 0, stream>>>(part_ws, attnl_ws, nchunk);
    attn_v_mfma <<<dim3(TV_/32, H_, B_), blk, 0, stream>>>(flag, q_ws, k_ws, vall_ws, maskl, attnv);

    // output projections (MFMA, external dtype epilogue)
    gemm_mfma<true><<<dim3(425, 2), blk, 0, stream>>>(flag, attnv,    wovb, bovf, d_out, 0,        VD_, E_, 1.0f);
    gemm_mfma<true><<<dim3(8,   6), blk, 0, stream>>>(flag, attnl_ws, wolb, bolf, d_out, outl_off, LD_, E_, 1.0f);
}